// Round 11
// baseline (501.198 us; speedup 1.0000x reference)
//
#include <hip/hip_runtime.h>
#include <math.h>

// Mesh encoder: 4x (spiral conv + ELU + sparse pool) + final GEMM.
// VERTS = [65536, 16384, 4096, 1024, 256], SEQ=9, CH=[3,32,64,128,256], B=16.
//
// R10: sorted edges (CSR perm) -> L2-local merged atomics; XCD batch pinning.
// R11: software-pipelined gathers — per-wave vertex table loaded upfront,
// rotating 2-buffer issue(u+1)-before-compute(u) k-unit pipeline, L0 fully
// pre-loaded. Forces ~8-16 outstanding gathers/wave (R10 compiler chose 2,
// VGPR=64, latency-bound at VALU 13%).

#define SEQL 9

typedef __attribute__((ext_vector_type(8))) short bf16x8;
typedef __attribute__((ext_vector_type(4))) float f32x4;

__device__ __forceinline__ unsigned short f2bf_rne(float f) {
    unsigned u = __builtin_bit_cast(unsigned, f);
    u = (u + 0x7FFFu + ((u >> 16) & 1u)) >> 16;
    return (unsigned short)u;
}
__device__ __forceinline__ float bf2f(unsigned short h) {
    unsigned u = ((unsigned)h) << 16;
    return __builtin_bit_cast(float, u);
}

// split 8 fp32 -> bf16 hi (trunc) + bf16 lo (trunc of exact residual)
__device__ __forceinline__ void cvt8(const float* xf, bf16x8& ah, bf16x8& al) {
    unsigned hu[4], lu[4];
#pragma unroll
    for (int p = 0; p < 4; ++p) {
        const unsigned u0 = __builtin_bit_cast(unsigned, xf[2 * p]);
        const unsigned u1 = __builtin_bit_cast(unsigned, xf[2 * p + 1]);
        const float h0 = __builtin_bit_cast(float, u0 & 0xFFFF0000u);
        const float h1 = __builtin_bit_cast(float, u1 & 0xFFFF0000u);
        const float l0 = xf[2 * p] - h0;
        const float l1 = xf[2 * p + 1] - h1;
        hu[p] = __builtin_amdgcn_perm(u1, u0, 0x07060302u);
        lu[p] = __builtin_amdgcn_perm(__builtin_bit_cast(unsigned, l1),
                                      __builtin_bit_cast(unsigned, l0),
                                      0x07060302u);
    }
    struct U4 { unsigned a, b, c, d; };
    ah = __builtin_bit_cast(bf16x8, U4{hu[0], hu[1], hu[2], hu[3]});
    al = __builtin_bit_cast(bf16x8, U4{lu[0], lu[1], lu[2], lu[3]});
}

// ---------- prep ----------

template<int CIN, int CINP, int COUT, int K>
__global__ __launch_bounds__(256)
void wt_prep(const float* __restrict__ W, unsigned short* __restrict__ WTh,
             unsigned short* __restrict__ WTl)
{
    const int t = blockIdx.x * 256 + threadIdx.x;
    if (t >= COUT * K) return;
    const int co = t / K, k = t % K;
    const int s = k / CINP, c = k % CINP;
    float w = (s < 9 && c < CIN) ? W[(size_t)(s * CIN + c) * COUT + co] : 0.0f;
    unsigned short h = f2bf_rne(w);
    WTh[t] = h;
    WTl[t] = f2bf_rne(w - bf2f(h));
}

__global__ __launch_bounds__(256)
void build_xp4(const float* __restrict__ x, float* __restrict__ xp4)
{
    const int t = blockIdx.x * 256 + threadIdx.x;   // 16*65536
    const float* p = x + (size_t)t * 3;
    *(float4*)(xp4 + (size_t)t * 4) = make_float4(p[0], p[1], p[2], 0.0f);
}

// ---------- CSR builders (row-sorted edge order) ----------

__global__ __launch_bounds__(256)
void hist_edges(const int* __restrict__ r0, const int* __restrict__ r1,
                const int* __restrict__ r2, const int* __restrict__ r3,
                int* c0, int* c1, int* c2, int* c3)
{
    const int g = blockIdx.x * 256 + threadIdx.x;
    if (g < 49152)      atomicAdd(&c0[r0[g]], 1);
    else if (g < 61440) atomicAdd(&c1[r1[g - 49152]], 1);
    else if (g < 64512) atomicAdd(&c2[r2[g - 61440]], 1);
    else if (g < 65280) atomicAdd(&c3[r3[g - 64512]], 1);
}

struct ScanTasks { const int* in[4]; int* out[4]; int n[4]; };

__global__ __launch_bounds__(256)
void scan_multi(ScanTasks T)
{
    const int* in  = T.in[blockIdx.x];
    int*       out = T.out[blockIdx.x];
    const int  n   = T.n[blockIdx.x];
    __shared__ int lds[256];
    const int tid = threadIdx.x;
    const int chunk = (n + 255) / 256;
    const int base = tid * chunk;
    int s = 0;
    for (int i = 0; i < chunk; ++i) { int p = base + i; if (p < n) s += in[p]; }
    lds[tid] = s; __syncthreads();
    int acc = s;
    for (int off = 1; off < 256; off <<= 1) {
        int t = (tid >= off) ? lds[tid - off] : 0;
        __syncthreads();
        acc += t; lds[tid] = acc;
        __syncthreads();
    }
    int run = acc - s;
    for (int i = 0; i < chunk; ++i) { int p = base + i; if (p < n) { out[p] = run; run += in[p]; } }
    if (tid == 255) out[n] = run;
}

__global__ __launch_bounds__(256)
void scatter_edges(const int* __restrict__ r0, const int* __restrict__ r1,
                   const int* __restrict__ r2, const int* __restrict__ r3,
                   const int* s0, const int* s1, const int* s2, const int* s3,
                   int* u0, int* u1, int* u2, int* u3,
                   int* p0, int* p1, int* p2, int* p3)
{
    const int g = blockIdx.x * 256 + threadIdx.x;
    if (g < 49152)      { int k = g;         int r = r0[k]; p0[s0[r] + atomicAdd(&u0[r], 1)] = k; }
    else if (g < 61440) { int k = g - 49152; int r = r1[k]; p1[s1[r] + atomicAdd(&u1[r], 1)] = k; }
    else if (g < 64512) { int k = g - 61440; int r = r2[k]; p2[s2[r] + atomicAdd(&u2[r], 1)] = k; }
    else if (g < 65280) { int k = g - 64512; int r = r3[k]; p3[s3[r] + atomicAdd(&u3[r], 1)] = k; }
}

// Sorted-position tables: eidxp[pos][16] (9 spiral verts + 0-pad),
// rw[pos]=row, vl[pos]=val, in row-sorted order.
__global__ __launch_bounds__(256)
void build_sorted(const int* __restrict__ p0, const int* __restrict__ p1,
                  const int* __restrict__ p2, const int* __restrict__ p3,
                  const int* __restrict__ c0, const int* __restrict__ i0,
                  const int* __restrict__ r0, const float* __restrict__ v0,
                  const int* __restrict__ c1, const int* __restrict__ i1,
                  const int* __restrict__ r1, const float* __restrict__ v1,
                  const int* __restrict__ c2, const int* __restrict__ i2,
                  const int* __restrict__ r2, const float* __restrict__ v2,
                  const int* __restrict__ c3, const int* __restrict__ i3,
                  const int* __restrict__ r3, const float* __restrict__ v3,
                  int* __restrict__ E, int* __restrict__ RW, float* __restrict__ VL)
{
    const int t = blockIdx.x * 256 + threadIdx.x;   // 65280
    if (t >= 65280) return;
    const int* perm; const int* col; const int* idx; const int* row;
    const float* val; int lp;
    if (t < 49152)      { perm = p0; col = c0; idx = i0; row = r0; val = v0; lp = t; }
    else if (t < 61440) { perm = p1; col = c1; idx = i1; row = r1; val = v1; lp = t - 49152; }
    else if (t < 64512) { perm = p2; col = c2; idx = i2; row = r2; val = v2; lp = t - 61440; }
    else                { perm = p3; col = c3; idx = i3; row = r3; val = v3; lp = t - 64512; }
    const int e = perm[lp];
    const int cv = col[e];
    int* Ep = E + (size_t)t * 16;
#pragma unroll
    for (int s = 0; s < SEQL; ++s) Ep[s] = idx[cv * SEQL + s];
#pragma unroll
    for (int s = SEQL; s < 16; ++s) Ep[s] = 0;
    RW[t] = row[e];
    VL[t] = val[e];
}

// ---------- fused conv+ELU+pool, edge-parallel, pipelined gathers ----------
// Wave = ES groups of 16 sorted edges x 1 batch x cs-slice of couts.
// A rows = 16 edges (lane&15); D: col=lane&15 (co), row=(lane>>4)*4+reg (edge).
template<int CIN, int CINP, int COUT, int K, int ES, int CS, int WGB>
__global__ __launch_bounds__(256, 2)
void conv_pool_mfma(const float* __restrict__ xin,   // [16][NV][CINP]
                    const int* __restrict__ eidxp,   // [nnz][16] sorted order
                    const int* __restrict__ rw,      // [nnz] sorted rows
                    const float* __restrict__ vl,    // [nnz] sorted vals
                    const unsigned short* __restrict__ WTh,
                    const unsigned short* __restrict__ WTl,
                    const float* __restrict__ bias,
                    float* __restrict__ xout,        // [16][NVOUT][COUT], zeroed
                    int NV, int NVOUT)
{
    constexpr int NT = COUT / 16 / CS;

    const int tid  = threadIdx.x;
    const int lane = tid & 63, wid = tid >> 6;
    const int b16  = lane & 15, g = lane >> 4;

    int rr = blockIdx.x;
    const int q = rr & 7; rr >>= 3;
    const int wgb = rr % WGB; rr /= WGB;
    const int cs = rr % CS;
    const int pass = rr / CS;
    const int b   = q + 8 * pass;                 // batch (XCD-pinned)
    const int co0 = cs * (NT * 16);
    const int e_base = (wgb * 4 + wid) * (ES * 16);

    f32x4 acc[ES][NT];
#pragma unroll
    for (int es = 0; es < ES; ++es)
#pragma unroll
        for (int nt = 0; nt < NT; ++nt) {
            const float bv = bias[co0 + nt * 16 + b16];
            acc[es][nt] = (f32x4){bv, bv, bv, bv};
        }

    const float* xb = xin + (size_t)b * NV * CINP;

    if constexpr (CINP == 4) {
        // L0: K=64, 2 k-steps; lane j: s = ks*8 + g*2 + j/4, c = j%4.
        // Pre-issue ALL eidx + ALL gathers (16 outstanding float4).
        int2 ev[ES][2];
#pragma unroll
        for (int es = 0; es < ES; ++es)
#pragma unroll
            for (int ks = 0; ks < 2; ++ks) {
                const int e = e_base + es * 16 + b16;
                ev[es][ks] = *(const int2*)(eidxp + (size_t)e * 16 + ks * 8 + g * 2);
            }
        float4 xa[ES][2], xbv[ES][2];
#pragma unroll
        for (int es = 0; es < ES; ++es)
#pragma unroll
            for (int ks = 0; ks < 2; ++ks) {
                xa[es][ks]  = *(const float4*)(xb + (size_t)ev[es][ks].x * 4);
                xbv[es][ks] = *(const float4*)(xb + (size_t)ev[es][ks].y * 4);
            }
#pragma unroll
        for (int ks = 0; ks < 2; ++ks) {
            bf16x8 wh[NT], wl[NT];
#pragma unroll
            for (int nt = 0; nt < NT; ++nt) {
                const size_t wo = (size_t)(co0 + nt * 16 + b16) * K + ks * 32 + g * 8;
                wh[nt] = *(const bf16x8*)(WTh + wo);
                wl[nt] = *(const bf16x8*)(WTl + wo);
            }
#pragma unroll
            for (int es = 0; es < ES; ++es) {
                float xf[8];
                *(float4*)&xf[0] = xa[es][ks];
                *(float4*)&xf[4] = xbv[es][ks];
                bf16x8 ah, al; cvt8(xf, ah, al);
#pragma unroll
                for (int nt = 0; nt < NT; ++nt) {
                    acc[es][nt] = __builtin_amdgcn_mfma_f32_16x16x32_bf16(ah, wh[nt], acc[es][nt], 0, 0, 0);
                    acc[es][nt] = __builtin_amdgcn_mfma_f32_16x16x32_bf16(al, wh[nt], acc[es][nt], 0, 0, 0);
                    acc[es][nt] = __builtin_amdgcn_mfma_f32_16x16x32_bf16(ah, wl[nt], acc[es][nt], 0, 0, 0);
                }
            }
        }
    } else {
        constexpr int KPS = CIN / 32;
        constexpr int NU  = SEQL * KPS;
        // Vertex table upfront: 12 slots (9 used) per edge-group.
        int vtab[ES][12];
#pragma unroll
        for (int es = 0; es < ES; ++es)
#pragma unroll
            for (int t4 = 0; t4 < 3; ++t4) {
                const int e = e_base + es * 16 + b16;
                const int4 q4 = *(const int4*)(eidxp + (size_t)e * 16 + t4 * 4);
                vtab[es][t4 * 4 + 0] = q4.x; vtab[es][t4 * 4 + 1] = q4.y;
                vtab[es][t4 * 4 + 2] = q4.z; vtab[es][t4 * 4 + 3] = q4.w;
            }

        float4 A0[ES], B0[ES], A1[ES], B1[ES];
        // issue unit 0
#pragma unroll
        for (int es = 0; es < ES; ++es) {
            const float* xp = xb + (size_t)vtab[es][0] * CIN + g * 8;
            A0[es] = *(const float4*)xp;
            B0[es] = *(const float4*)(xp + 4);
        }
#pragma unroll
        for (int u = 0; u < NU; ++u) {
            // issue unit u+1 into the other buffer (addresses from vtab regs)
            if (u + 1 < NU) {
                const int s1 = (u + 1) / KPS, kk1 = (u + 1) % KPS;
#pragma unroll
                for (int es = 0; es < ES; ++es) {
                    const float* xp = xb + (size_t)vtab[es][s1] * CIN + kk1 * 32 + g * 8;
                    if (u & 1) { A0[es] = *(const float4*)xp; B0[es] = *(const float4*)(xp + 4); }
                    else       { A1[es] = *(const float4*)xp; B1[es] = *(const float4*)(xp + 4); }
                }
            }
            // compute unit u
            bf16x8 wh[NT], wl[NT];
#pragma unroll
            for (int nt = 0; nt < NT; ++nt) {
                const size_t wo = (size_t)(co0 + nt * 16 + b16) * K + u * 32 + g * 8;
                wh[nt] = *(const bf16x8*)(WTh + wo);
                wl[nt] = *(const bf16x8*)(WTl + wo);
            }
#pragma unroll
            for (int es = 0; es < ES; ++es) {
                float xf[8];
                if (u & 1) { *(float4*)&xf[0] = A1[es]; *(float4*)&xf[4] = B1[es]; }
                else       { *(float4*)&xf[0] = A0[es]; *(float4*)&xf[4] = B0[es]; }
                bf16x8 ah, al; cvt8(xf, ah, al);
#pragma unroll
                for (int nt = 0; nt < NT; ++nt) {
                    acc[es][nt] = __builtin_amdgcn_mfma_f32_16x16x32_bf16(ah, wh[nt], acc[es][nt], 0, 0, 0);
                    acc[es][nt] = __builtin_amdgcn_mfma_f32_16x16x32_bf16(al, wh[nt], acc[es][nt], 0, 0, 0);
                    acc[es][nt] = __builtin_amdgcn_mfma_f32_16x16x32_bf16(ah, wl[nt], acc[es][nt], 0, 0, 0);
                }
            }
        }
    }

    // Epilogue: rows SORTED -> merge equal-row runs, one atomic per run.
#pragma unroll
    for (int es = 0; es < ES; ++es) {
        const int eq = e_base + es * 16 + g * 4;
        const int4   r4 = *(const int4*)(rw + eq);
        const float4 v4 = *(const float4*)(vl + eq);
        const int   ra[4] = {r4.x, r4.y, r4.z, r4.w};
        const float va[4] = {v4.x, v4.y, v4.z, v4.w};
#pragma unroll
        for (int nt = 0; nt < NT; ++nt) {
            float sum = 0.0f;
#pragma unroll
            for (int qq = 0; qq < 4; ++qq) {
                float y = acc[es][nt][qq];
                y = (y > 0.0f) ? y : __expf(y) - 1.0f;
                sum = fmaf(va[qq], y, sum);
                if (qq == 3 || ra[qq + 1] != ra[qq]) {
                    atomicAdd(xout + ((size_t)b * NVOUT + ra[qq]) * COUT + co0 + nt * 16 + b16, sum);
                    sum = 0.0f;
                }
            }
        }
    }
}

// ---------- final GEMM ----------
__global__ __launch_bounds__(256)
void final_gemm_partial(const float* __restrict__ x4,   // [16][65536]
                        const float* __restrict__ Wf,   // [65536][256]
                        float* __restrict__ part)       // [256][16][256]
{
    __shared__ float xs[256 * 20];
    const int j0 = blockIdx.x * 256;
    const int t  = threadIdx.x;

#pragma unroll
    for (int it = 0; it < 16; ++it)
        xs[t * 20 + it] = x4[(size_t)it * 65536 + j0 + t];
    __syncthreads();

    float acc[16];
#pragma unroll
    for (int b = 0; b < 16; ++b) acc[b] = 0.0f;

#pragma unroll 4
    for (int jj = 0; jj < 256; ++jj) {
        const float w = Wf[(size_t)(j0 + jj) * 256 + t];
#pragma unroll
        for (int b4 = 0; b4 < 4; ++b4) {
            const float4 xv = *(const float4*)(xs + jj * 20 + b4 * 4);
            acc[b4 * 4 + 0] = fmaf(xv.x, w, acc[b4 * 4 + 0]);
            acc[b4 * 4 + 1] = fmaf(xv.y, w, acc[b4 * 4 + 1]);
            acc[b4 * 4 + 2] = fmaf(xv.z, w, acc[b4 * 4 + 2]);
            acc[b4 * 4 + 3] = fmaf(xv.w, w, acc[b4 * 4 + 3]);
        }
    }
#pragma unroll
    for (int b = 0; b < 16; ++b)
        part[(size_t)blockIdx.x * 4096 + b * 256 + t] = acc[b];
}

__global__ __launch_bounds__(256)
void final_reduce(const float* __restrict__ part, const float* __restrict__ bf,
                  float* __restrict__ out)
{
    const int b = blockIdx.x, l = threadIdx.x;
    float s = 0.0f;
    for (int jb = 0; jb < 256; ++jb) s += part[(size_t)jb * 4096 + b * 256 + l];
    out[b * 256 + l] = s + bf[l];
}

// ---------- launch ----------
extern "C" void kernel_launch(void* const* d_in, const int* in_sizes, int n_in,
                              void* d_out, int out_size, void* d_ws, size_t ws_size,
                              hipStream_t stream)
{
    const float* x    = (const float*)d_in[0];
    const int*   idx0 = (const int*)d_in[1];
    const int*   row0 = (const int*)d_in[2];
    const int*   col0 = (const int*)d_in[3];
    const float* val0 = (const float*)d_in[4];
    const float* W0   = (const float*)d_in[5];
    const float* b0   = (const float*)d_in[6];
    const int*   idx1 = (const int*)d_in[7];
    const int*   row1 = (const int*)d_in[8];
    const int*   col1 = (const int*)d_in[9];
    const float* val1 = (const float*)d_in[10];
    const float* W1   = (const float*)d_in[11];
    const float* b1   = (const float*)d_in[12];
    const int*   idx2 = (const int*)d_in[13];
    const int*   row2 = (const int*)d_in[14];
    const int*   col2 = (const int*)d_in[15];
    const float* val2 = (const float*)d_in[16];
    const float* W2   = (const float*)d_in[17];
    const float* b2   = (const float*)d_in[18];
    const int*   idx3 = (const int*)d_in[19];
    const int*   row3 = (const int*)d_in[20];
    const int*   col3 = (const int*)d_in[21];
    const float* val3 = (const float*)d_in[22];
    const float* W3   = (const float*)d_in[23];
    const float* b3   = (const float*)d_in[24];
    const float* Wf   = (const float*)d_in[25];
    const float* bf   = (const float*)d_in[26];
    float* out = (float*)d_out;

    float* ws = (float*)d_ws;
    // Aliased activation timeline (float offsets):
    float* x1   = ws + 0;         // [16][16384][32]  live L0->L1
    float* xp4  = ws + 8388608;   // [16][65536][4]   live prep->L0
    float* x2   = ws + 8388608;   // [16][4096][64]   live L1->L2 (xp4 dead)
    float* x3   = ws + 0;         // [16][1024][128]  live L2->L3 (x1 dead)
    float* x4   = ws + 2097152;   // [16][256][256]   live L3->final
    float* part = ws + 3145728;   // [256][16][256]   final phase
    unsigned short* wt = (unsigned short*)(ws + 12582912);
    unsigned short *WTh0 = wt,          *WTl0 = wt + 2048;
    unsigned short *WTh1 = wt + 4096,   *WTl1 = wt + 22528;
    unsigned short *WTh2 = wt + 40960,  *WTl2 = wt + 114688;
    unsigned short *WTh3 = wt + 188416, *WTl3 = wt + 483328;  // end 778240 u16
    int* EIDXP = (int*)(ws + 12972032);   // [65280][16]
    int* E0 = EIDXP;
    int* E1 = EIDXP + 49152 * 16;
    int* E2 = EIDXP + 61440 * 16;
    int* E3 = EIDXP + 64512 * 16;
    int* RW = (int*)(ws + 14016512);      // [65280]
    int *R0 = RW, *R1 = RW + 49152, *R2 = RW + 61440, *R3 = RW + 64512;
    float* VL = (ws + 14081792);          // [65280]
    float *V0 = VL, *V1 = VL + 49152, *V2 = VL + 61440, *V3 = VL + 64512;
    int* C = (int*)(ws + 14147072);       // CSR scratch
    int *c0 = C + 0,     *c1 = C + 16384, *c2 = C + 20480, *c3 = C + 21504;
    int *u0 = C + 21760, *u1 = C + 38144, *u2 = C + 42240, *u3 = C + 43264;
    int *s0 = C + 43520, *s1 = C + 59905, *s2 = C + 64002, *s3 = C + 65027;
    int *p0 = C + 65284, *p1 = C + 114436, *p2 = C + 126724, *p3 = C + 129796;
    // end: C + 130564 ints -> total ws usage ~57.1 MB

    // ---- prep + CSR ----
    hipMemsetAsync(C, 0, (size_t)43520 * sizeof(int), stream);   // c*, u*
    wt_prep<3,   4,   32,   64><<<   8, 256, 0, stream>>>(W0, WTh0, WTl0);
    wt_prep<32,  32,  64,  288><<<  72, 256, 0, stream>>>(W1, WTh1, WTl1);
    wt_prep<64,  64,  128, 576><<< 288, 256, 0, stream>>>(W2, WTh2, WTl2);
    wt_prep<128, 128, 256, 1152><<<1152, 256, 0, stream>>>(W3, WTh3, WTl3);
    build_xp4<<<4096, 256, 0, stream>>>(x, xp4);

    hist_edges<<<255, 256, 0, stream>>>(row0, row1, row2, row3, c0, c1, c2, c3);
    ScanTasks T;
    T.in[0] = c0; T.out[0] = s0; T.n[0] = 16384;
    T.in[1] = c1; T.out[1] = s1; T.n[1] = 4096;
    T.in[2] = c2; T.out[2] = s2; T.n[2] = 1024;
    T.in[3] = c3; T.out[3] = s3; T.n[3] = 256;
    scan_multi<<<4, 256, 0, stream>>>(T);
    scatter_edges<<<255, 256, 0, stream>>>(row0, row1, row2, row3,
                                           s0, s1, s2, s3, u0, u1, u2, u3,
                                           p0, p1, p2, p3);
    build_sorted<<<255, 256, 0, stream>>>(p0, p1, p2, p3,
                                          col0, idx0, row0, val0,
                                          col1, idx1, row1, val1,
                                          col2, idx2, row2, val2,
                                          col3, idx3, row3, val3,
                                          EIDXP, RW, VL);

    // ---- levels ----
    // L0: ES=4, CS=1, NT=2, WGB=192 -> grid 8*192*1*2 = 3072
    hipMemsetAsync(x1, 0, (size_t)8388608 * 4, stream);
    conv_pool_mfma<3, 4, 32, 64, 4, 1, 192><<<3072, 256, 0, stream>>>(
        xp4, E0, R0, V0, WTh0, WTl0, b0, x1, 65536, 16384);

    // L1: ES=2, CS=2, NT=2, WGB=96 -> grid 8*96*2*2 = 3072
    hipMemsetAsync(x2, 0, (size_t)4194304 * 4, stream);
    conv_pool_mfma<32, 32, 64, 288, 2, 2, 96><<<3072, 256, 0, stream>>>(
        x1, E1, R1, V1, WTh1, WTl1, b1, x2, 16384, 4096);

    // L2 + L3 (x1 dead -> zero x3|x4 region in one memset)
    hipMemsetAsync(x3, 0, (size_t)3145728 * 4, stream);
    // L2: ES=2, CS=4, NT=2, WGB=24 -> grid 8*24*4*2 = 1536
    conv_pool_mfma<64, 64, 128, 576, 2, 4, 24><<<1536, 256, 0, stream>>>(
        x2, E2, R2, V2, WTh2, WTl2, b2, x3, 4096, 1024);
    // L3: ES=2, CS=8, NT=2, WGB=6 -> grid 8*6*8*2 = 768
    conv_pool_mfma<128, 128, 256, 1152, 2, 8, 6><<<768, 256, 0, stream>>>(
        x3, E3, R3, V3, WTh3, WTl3, b3, x4, 1024, 256);

    // ---- final GEMM ----
    final_gemm_partial<<<256, 256, 0, stream>>>(x4, Wf, part);
    final_reduce<<<16, 256, 0, stream>>>(part, bf, out);
}

// Round 12
// 338.411 us; speedup vs baseline: 1.4810x; 1.4810x over previous
//
#include <hip/hip_runtime.h>
#include <math.h>

// Mesh encoder: 4x (spiral conv + ELU + sparse pool) + final GEMM.
// VERTS = [65536, 16384, 4096, 1024, 256], SEQ=9, CH=[3,32,64,128,256], B=16.
//
// R12: vertex-major [V][C][16] activations; wave = ES edges x ALL 16 batches.
// MFMA operands swapped: A = W^T (rows = couts), B = gathered x (cols =
// batches). Gathers: wave-uniform vertex -> 8 scalar loads hitting 4
// contiguous 64B segments (vs 64 scattered lines in batch-split R7-R11).
// W in [K/32][COUT][32] so W-frag load is one coalesced 1KB instr.
// Sorted edges (CSR perm) + run-merged atomics on contiguous batch-lanes.
// 3-MFMA hi/lo error split retained.

#define SEQL 9

typedef __attribute__((ext_vector_type(8))) short bf16x8;
typedef __attribute__((ext_vector_type(4))) float f32x4;

__device__ __forceinline__ unsigned short f2bf_rne(float f) {
    unsigned u = __builtin_bit_cast(unsigned, f);
    u = (u + 0x7FFFu + ((u >> 16) & 1u)) >> 16;
    return (unsigned short)u;
}
__device__ __forceinline__ float bf2f(unsigned short h) {
    unsigned u = ((unsigned)h) << 16;
    return __builtin_bit_cast(float, u);
}

// split 8 fp32 -> bf16 hi (trunc) + bf16 lo (trunc of exact residual)
__device__ __forceinline__ void cvt8(const float* xf, bf16x8& ah, bf16x8& al) {
    unsigned hu[4], lu[4];
#pragma unroll
    for (int p = 0; p < 4; ++p) {
        const unsigned u0 = __builtin_bit_cast(unsigned, xf[2 * p]);
        const unsigned u1 = __builtin_bit_cast(unsigned, xf[2 * p + 1]);
        const float h0 = __builtin_bit_cast(float, u0 & 0xFFFF0000u);
        const float h1 = __builtin_bit_cast(float, u1 & 0xFFFF0000u);
        const float l0 = xf[2 * p] - h0;
        const float l1 = xf[2 * p + 1] - h1;
        hu[p] = __builtin_amdgcn_perm(u1, u0, 0x07060302u);
        lu[p] = __builtin_amdgcn_perm(__builtin_bit_cast(unsigned, l1),
                                      __builtin_bit_cast(unsigned, l0),
                                      0x07060302u);
    }
    struct U4 { unsigned a, b, c, d; };
    ah = __builtin_bit_cast(bf16x8, U4{hu[0], hu[1], hu[2], hu[3]});
    al = __builtin_bit_cast(bf16x8, U4{lu[0], lu[1], lu[2], lu[3]});
}

// ---------- prep ----------

// W [9*CIN][COUT] fp32 -> WTh/WTl [K/32][COUT][32] bf16 (zero-padded).
template<int CIN, int CINP, int COUT, int K>
__global__ __launch_bounds__(256)
void wt_prep(const float* __restrict__ W, unsigned short* __restrict__ WTh,
             unsigned short* __restrict__ WTl)
{
    const int t = blockIdx.x * 256 + threadIdx.x;
    if (t >= COUT * K) return;
    const int u = t / (COUT * 32);
    const int rem = t % (COUT * 32);
    const int co = rem / 32, kk = rem % 32;
    const int k = u * 32 + kk;
    const int s = k / CINP, c = k % CINP;
    float w = (s < 9 && c < CIN) ? W[(size_t)(s * CIN + c) * COUT + co] : 0.0f;
    unsigned short h = f2bf_rne(w);
    WTh[t] = h;
    WTl[t] = f2bf_rne(w - bf2f(h));
}

// x [16][65536][3] -> x0T [65536][4][16] (c=3 zero pad)
__global__ __launch_bounds__(256)
void build_x0T(const float* __restrict__ x, float* __restrict__ x0T)
{
    const int f = blockIdx.x * 256 + threadIdx.x;   // 65536*64
    const int v = f >> 6, rem = f & 63;
    const int c = rem >> 4, b = rem & 15;
    x0T[f] = (c < 3) ? x[((size_t)b * 65536 + v) * 3 + c] : 0.0f;
}

// ---------- CSR builders (row-sorted edge order) ----------

__global__ __launch_bounds__(256)
void hist_edges(const int* __restrict__ r0, const int* __restrict__ r1,
                const int* __restrict__ r2, const int* __restrict__ r3,
                int* c0, int* c1, int* c2, int* c3)
{
    const int g = blockIdx.x * 256 + threadIdx.x;
    if (g < 49152)      atomicAdd(&c0[r0[g]], 1);
    else if (g < 61440) atomicAdd(&c1[r1[g - 49152]], 1);
    else if (g < 64512) atomicAdd(&c2[r2[g - 61440]], 1);
    else if (g < 65280) atomicAdd(&c3[r3[g - 64512]], 1);
}

struct ScanTasks { const int* in[4]; int* out[4]; int n[4]; };

__global__ __launch_bounds__(256)
void scan_multi(ScanTasks T)
{
    const int* in  = T.in[blockIdx.x];
    int*       out = T.out[blockIdx.x];
    const int  n   = T.n[blockIdx.x];
    __shared__ int lds[256];
    const int tid = threadIdx.x;
    const int chunk = (n + 255) / 256;
    const int base = tid * chunk;
    int s = 0;
    for (int i = 0; i < chunk; ++i) { int p = base + i; if (p < n) s += in[p]; }
    lds[tid] = s; __syncthreads();
    int acc = s;
    for (int off = 1; off < 256; off <<= 1) {
        int t = (tid >= off) ? lds[tid - off] : 0;
        __syncthreads();
        acc += t; lds[tid] = acc;
        __syncthreads();
    }
    int run = acc - s;
    for (int i = 0; i < chunk; ++i) { int p = base + i; if (p < n) { out[p] = run; run += in[p]; } }
    if (tid == 255) out[n] = run;
}

__global__ __launch_bounds__(256)
void scatter_edges(const int* __restrict__ r0, const int* __restrict__ r1,
                   const int* __restrict__ r2, const int* __restrict__ r3,
                   const int* s0, const int* s1, const int* s2, const int* s3,
                   int* u0, int* u1, int* u2, int* u3,
                   int* p0, int* p1, int* p2, int* p3)
{
    const int g = blockIdx.x * 256 + threadIdx.x;
    if (g < 49152)      { int k = g;         int r = r0[k]; p0[s0[r] + atomicAdd(&u0[r], 1)] = k; }
    else if (g < 61440) { int k = g - 49152; int r = r1[k]; p1[s1[r] + atomicAdd(&u1[r], 1)] = k; }
    else if (g < 64512) { int k = g - 61440; int r = r2[k]; p2[s2[r] + atomicAdd(&u2[r], 1)] = k; }
    else if (g < 65280) { int k = g - 64512; int r = r3[k]; p3[s3[r] + atomicAdd(&u3[r], 1)] = k; }
}

// Sorted-position tables: eidxp[pos][16] (9 spiral verts + 0-pad),
// rw[pos]=row, vl[pos]=val, in row-sorted order.
__global__ __launch_bounds__(256)
void build_sorted(const int* __restrict__ p0, const int* __restrict__ p1,
                  const int* __restrict__ p2, const int* __restrict__ p3,
                  const int* __restrict__ c0, const int* __restrict__ i0,
                  const int* __restrict__ r0, const float* __restrict__ v0,
                  const int* __restrict__ c1, const int* __restrict__ i1,
                  const int* __restrict__ r1, const float* __restrict__ v1,
                  const int* __restrict__ c2, const int* __restrict__ i2,
                  const int* __restrict__ r2, const float* __restrict__ v2,
                  const int* __restrict__ c3, const int* __restrict__ i3,
                  const int* __restrict__ r3, const float* __restrict__ v3,
                  int* __restrict__ E, int* __restrict__ RW, float* __restrict__ VL)
{
    const int t = blockIdx.x * 256 + threadIdx.x;   // 65280
    if (t >= 65280) return;
    const int* perm; const int* col; const int* idx; const int* row;
    const float* val; int lp;
    if (t < 49152)      { perm = p0; col = c0; idx = i0; row = r0; val = v0; lp = t; }
    else if (t < 61440) { perm = p1; col = c1; idx = i1; row = r1; val = v1; lp = t - 49152; }
    else if (t < 64512) { perm = p2; col = c2; idx = i2; row = r2; val = v2; lp = t - 61440; }
    else                { perm = p3; col = c3; idx = i3; row = r3; val = v3; lp = t - 64512; }
    const int e = perm[lp];
    const int cv = col[e];
    int* Ep = E + (size_t)t * 16;
#pragma unroll
    for (int s = 0; s < SEQL; ++s) Ep[s] = idx[cv * SEQL + s];
#pragma unroll
    for (int s = SEQL; s < 16; ++s) Ep[s] = 0;
    RW[t] = row[e];
    VL[t] = val[e];
}

// ---------- fused conv+ELU+pool: wave = ES edges x 16 batches ----------
// A = W^T tile (rows = 16 couts), B = gathered x (cols = 16 batches).
// D: row (g*4+q) = co_local, col (lane&15) = batch  [m89 mapping].
template<int CINP, int COUT, int K, int ES, int CS, int WGB>
__global__ __launch_bounds__(256)
void conv_pool_mfma(const float* __restrict__ xin,   // [NV][CINP][16]
                    const int* __restrict__ eidxp,   // [nnz][16] sorted order
                    const int* __restrict__ rw,      // [nnz] sorted rows
                    const float* __restrict__ vl,    // [nnz] sorted vals
                    const unsigned short* __restrict__ WTh,  // [K/32][COUT][32]
                    const unsigned short* __restrict__ WTl,
                    const float* __restrict__ bias,
                    float* __restrict__ xout)        // [NVOUT][COUT][16], zeroed
{
    constexpr int NT = COUT / 16 / CS;
    constexpr int NU = K / 32;

    const int lane = threadIdx.x & 63, wid = threadIdx.x >> 6;
    const int b16 = lane & 15, g = lane >> 4;

    const int bid = blockIdx.x;
    const int wgb = bid % WGB, cs = bid / WGB;
    const int co0 = cs * (NT * 16);
    const int e0  = (wgb * 4 + wid) * ES;

    float4 bini[NT];
#pragma unroll
    for (int nt = 0; nt < NT; ++nt)
        bini[nt] = *(const float4*)(bias + co0 + nt * 16 + g * 4);

    f32x4 acc[ES][NT];
#pragma unroll
    for (int es = 0; es < ES; ++es)
#pragma unroll
        for (int nt = 0; nt < NT; ++nt)
            acc[es][nt] = (f32x4){bini[nt].x, bini[nt].y, bini[nt].z, bini[nt].w};

    if constexpr (CINP == 4) {
        // L0: K=64, 2 k-steps. k=u*32+g*8+j -> s=u*8+g*2+j/4, c=j%4.
#pragma unroll
        for (int u = 0; u < 2; ++u) {
            bf16x8 wh[NT], wl[NT];
#pragma unroll
            for (int nt = 0; nt < NT; ++nt) {
                const size_t wo = (size_t)u * COUT * 32 + (co0 + nt * 16 + b16) * 32 + g * 8;
                wh[nt] = *(const bf16x8*)(WTh + wo);
                wl[nt] = *(const bf16x8*)(WTl + wo);
            }
#pragma unroll
            for (int es = 0; es < ES; ++es) {
                const int2 ev = *(const int2*)(eidxp + (size_t)(e0 + es) * 16 + u * 8 + g * 2);
                const float* xa = xin + (size_t)ev.x * 64;
                const float* xc = xin + (size_t)ev.y * 64;
                float xf[8];
#pragma unroll
                for (int j = 0; j < 4; ++j) xf[j]     = xa[j * 16 + b16];
#pragma unroll
                for (int j = 0; j < 4; ++j) xf[4 + j] = xc[j * 16 + b16];
                bf16x8 xh, xl; cvt8(xf, xh, xl);
#pragma unroll
                for (int nt = 0; nt < NT; ++nt) {
                    acc[es][nt] = __builtin_amdgcn_mfma_f32_16x16x32_bf16(wh[nt], xh, acc[es][nt], 0, 0, 0);
                    acc[es][nt] = __builtin_amdgcn_mfma_f32_16x16x32_bf16(wl[nt], xh, acc[es][nt], 0, 0, 0);
                    acc[es][nt] = __builtin_amdgcn_mfma_f32_16x16x32_bf16(wh[nt], xl, acc[es][nt], 0, 0, 0);
                }
            }
        }
    } else {
        constexpr int KPS = CINP / 32;
#pragma unroll 1
        for (int u = 0; u < NU; ++u) {
            const int s = u / KPS, kk = u % KPS;
            bf16x8 wh[NT], wl[NT];
#pragma unroll
            for (int nt = 0; nt < NT; ++nt) {
                const size_t wo = (size_t)u * COUT * 32 + (co0 + nt * 16 + b16) * 32 + g * 8;
                wh[nt] = *(const bf16x8*)(WTh + wo);
                wl[nt] = *(const bf16x8*)(WTl + wo);
            }
#pragma unroll
            for (int es = 0; es < ES; ++es) {
                const int vi = eidxp[(size_t)(e0 + es) * 16 + s];   // wave-uniform
                const float* xp = xin + ((size_t)vi * CINP + kk * 32) * 16;
                float xf[8];
#pragma unroll
                for (int j = 0; j < 8; ++j) xf[j] = xp[(g * 8 + j) * 16 + b16];
                bf16x8 xh, xl; cvt8(xf, xh, xl);
#pragma unroll
                for (int nt = 0; nt < NT; ++nt) {
                    acc[es][nt] = __builtin_amdgcn_mfma_f32_16x16x32_bf16(wh[nt], xh, acc[es][nt], 0, 0, 0);
                    acc[es][nt] = __builtin_amdgcn_mfma_f32_16x16x32_bf16(wl[nt], xh, acc[es][nt], 0, 0, 0);
                    acc[es][nt] = __builtin_amdgcn_mfma_f32_16x16x32_bf16(wh[nt], xl, acc[es][nt], 0, 0, 0);
                }
            }
        }
    }

    // Epilogue: per es, y = ELU(acc)*val[e]; merge runs of equal row
    // (wave-uniform compares, edges sorted by row), one atomic set per run.
    f32x4 mrg[NT];
#pragma unroll
    for (int nt = 0; nt < NT; ++nt) mrg[nt] = (f32x4){0.f, 0.f, 0.f, 0.f};
    int rprev = rw[e0];
#pragma unroll
    for (int es = 0; es < ES; ++es) {
        const int   r = rw[e0 + es];
        const float v = vl[e0 + es];
        if (r != rprev) {
#pragma unroll
            for (int nt = 0; nt < NT; ++nt)
#pragma unroll
                for (int q = 0; q < 4; ++q) {
                    atomicAdd(xout + (size_t)rprev * COUT * 16 + (co0 + nt * 16 + g * 4 + q) * 16 + b16,
                              mrg[nt][q]);
                    mrg[nt][q] = 0.0f;
                }
            rprev = r;
        }
#pragma unroll
        for (int nt = 0; nt < NT; ++nt)
#pragma unroll
            for (int q = 0; q < 4; ++q) {
                float y = acc[es][nt][q];
                y = (y > 0.0f) ? y : __expf(y) - 1.0f;
                mrg[nt][q] = fmaf(v, y, mrg[nt][q]);
            }
    }
#pragma unroll
    for (int nt = 0; nt < NT; ++nt)
#pragma unroll
        for (int q = 0; q < 4; ++q)
            atomicAdd(xout + (size_t)rprev * COUT * 16 + (co0 + nt * 16 + g * 4 + q) * 16 + b16,
                      mrg[nt][q]);
}

// ---------- final GEMM: x4T [65536 j][16 b] (j = v*256+c) ----------
__global__ __launch_bounds__(256)
void final_gemm_partial(const float* __restrict__ x4T,  // [65536][16]
                        const float* __restrict__ Wf,   // [65536][256]
                        float* __restrict__ part)       // [256][16][256]
{
    __shared__ float xs[256 * 16];
    const int j0 = blockIdx.x * 256;
    const int t  = threadIdx.x;

#pragma unroll
    for (int it = 0; it < 4; ++it) {
        const int f = t + it * 256;
        *(float4*)(xs + f * 4) = *(const float4*)(x4T + (size_t)j0 * 16 + f * 4);
    }
    __syncthreads();

    float acc[16];
#pragma unroll
    for (int b = 0; b < 16; ++b) acc[b] = 0.0f;

#pragma unroll 4
    for (int jj = 0; jj < 256; ++jj) {
        const float w = Wf[(size_t)(j0 + jj) * 256 + t];
#pragma unroll
        for (int b4 = 0; b4 < 4; ++b4) {
            const float4 xv = *(const float4*)(xs + jj * 16 + b4 * 4);
            acc[b4 * 4 + 0] = fmaf(xv.x, w, acc[b4 * 4 + 0]);
            acc[b4 * 4 + 1] = fmaf(xv.y, w, acc[b4 * 4 + 1]);
            acc[b4 * 4 + 2] = fmaf(xv.z, w, acc[b4 * 4 + 2]);
            acc[b4 * 4 + 3] = fmaf(xv.w, w, acc[b4 * 4 + 3]);
        }
    }
#pragma unroll
    for (int b = 0; b < 16; ++b)
        part[(size_t)blockIdx.x * 4096 + b * 256 + t] = acc[b];
}

__global__ __launch_bounds__(256)
void final_reduce(const float* __restrict__ part, const float* __restrict__ bf,
                  float* __restrict__ out)
{
    const int b = blockIdx.x, l = threadIdx.x;
    float s = 0.0f;
    for (int jb = 0; jb < 256; ++jb) s += part[(size_t)jb * 4096 + b * 256 + l];
    out[b * 256 + l] = s + bf[l];
}

// ---------- launch ----------
extern "C" void kernel_launch(void* const* d_in, const int* in_sizes, int n_in,
                              void* d_out, int out_size, void* d_ws, size_t ws_size,
                              hipStream_t stream)
{
    const float* x    = (const float*)d_in[0];
    const int*   idx0 = (const int*)d_in[1];
    const int*   row0 = (const int*)d_in[2];
    const int*   col0 = (const int*)d_in[3];
    const float* val0 = (const float*)d_in[4];
    const float* W0   = (const float*)d_in[5];
    const float* b0   = (const float*)d_in[6];
    const int*   idx1 = (const int*)d_in[7];
    const int*   row1 = (const int*)d_in[8];
    const int*   col1 = (const int*)d_in[9];
    const float* val1 = (const float*)d_in[10];
    const float* W1   = (const float*)d_in[11];
    const float* b1   = (const float*)d_in[12];
    const int*   idx2 = (const int*)d_in[13];
    const int*   row2 = (const int*)d_in[14];
    const int*   col2 = (const int*)d_in[15];
    const float* val2 = (const float*)d_in[16];
    const float* W2   = (const float*)d_in[17];
    const float* b2   = (const float*)d_in[18];
    const int*   idx3 = (const int*)d_in[19];
    const int*   row3 = (const int*)d_in[20];
    const int*   col3 = (const int*)d_in[21];
    const float* val3 = (const float*)d_in[22];
    const float* W3   = (const float*)d_in[23];
    const float* b3   = (const float*)d_in[24];
    const float* Wf   = (const float*)d_in[25];
    const float* bf   = (const float*)d_in[26];
    float* out = (float*)d_out;

    float* ws = (float*)d_ws;
    // Aliased activation timeline ([V][C][16] layouts, float offsets):
    float* x1   = ws + 0;         // [16384][32][16]  live L0->L1
    float* x0T  = ws + 8388608;   // [65536][4][16]   live prep->L0
    float* x2   = ws + 8388608;   // [4096][64][16]   live L1->L2 (x0T dead)
    float* x3   = ws + 0;         // [1024][128][16]  live L2->L3 (x1 dead)
    float* x4   = ws + 2097152;   // [256][256][16]   live L3->final
    float* part = ws + 3145728;   // [256][16][256]   final phase
    unsigned short* wt = (unsigned short*)(ws + 12582912);
    unsigned short *WTh0 = wt,          *WTl0 = wt + 2048;
    unsigned short *WTh1 = wt + 4096,   *WTl1 = wt + 22528;
    unsigned short *WTh2 = wt + 40960,  *WTl2 = wt + 114688;
    unsigned short *WTh3 = wt + 188416, *WTl3 = wt + 483328;  // end 778240 u16
    int* EIDXP = (int*)(ws + 12972032);   // [65280][16]
    int* E0 = EIDXP;
    int* E1 = EIDXP + 49152 * 16;
    int* E2 = EIDXP + 61440 * 16;
    int* E3 = EIDXP + 64512 * 16;
    int* RW = (int*)(ws + 14016512);      // [65280]
    int *R0 = RW, *R1 = RW + 49152, *R2 = RW + 61440, *R3 = RW + 64512;
    float* VL = (ws + 14081792);          // [65280]
    float *V0 = VL, *V1 = VL + 49152, *V2 = VL + 61440, *V3 = VL + 64512;
    int* C = (int*)(ws + 14147072);       // CSR scratch
    int *c0 = C + 0,     *c1 = C + 16384, *c2 = C + 20480, *c3 = C + 21504;
    int *u0 = C + 21760, *u1 = C + 38144, *u2 = C + 42240, *u3 = C + 43264;
    int *s0 = C + 43520, *s1 = C + 59905, *s2 = C + 64002, *s3 = C + 65027;
    int *p0 = C + 65284, *p1 = C + 114436, *p2 = C + 126724, *p3 = C + 129796;
    // end: C + 130564 ints -> total ws usage ~57.1 MB (same envelope as R10/R11)

    // ---- prep + CSR ----
    hipMemsetAsync(C, 0, (size_t)43520 * sizeof(int), stream);   // c*, u*
    wt_prep<3,   4,   32,   64><<<   8, 256, 0, stream>>>(W0, WTh0, WTl0);
    wt_prep<32,  32,  64,  288><<<  72, 256, 0, stream>>>(W1, WTh1, WTl1);
    wt_prep<64,  64,  128, 576><<< 288, 256, 0, stream>>>(W2, WTh2, WTl2);
    wt_prep<128, 128, 256, 1152><<<1152, 256, 0, stream>>>(W3, WTh3, WTl3);
    build_x0T<<<16384, 256, 0, stream>>>(x, x0T);

    hist_edges<<<255, 256, 0, stream>>>(row0, row1, row2, row3, c0, c1, c2, c3);
    ScanTasks T;
    T.in[0] = c0; T.out[0] = s0; T.n[0] = 16384;
    T.in[1] = c1; T.out[1] = s1; T.n[1] = 4096;
    T.in[2] = c2; T.out[2] = s2; T.n[2] = 1024;
    T.in[3] = c3; T.out[3] = s3; T.n[3] = 256;
    scan_multi<<<4, 256, 0, stream>>>(T);
    scatter_edges<<<255, 256, 0, stream>>>(row0, row1, row2, row3,
                                           s0, s1, s2, s3, u0, u1, u2, u3,
                                           p0, p1, p2, p3);
    build_sorted<<<255, 256, 0, stream>>>(p0, p1, p2, p3,
                                          col0, idx0, row0, val0,
                                          col1, idx1, row1, val1,
                                          col2, idx2, row2, val2,
                                          col3, idx3, row3, val3,
                                          EIDXP, RW, VL);

    // ---- levels ----
    // L0: ES=4, CS=1, NT=2; edges/block=16; WGB=3072 -> 3072 blocks (12288 waves)
    hipMemsetAsync(x1, 0, (size_t)8388608 * 4, stream);
    conv_pool_mfma<4, 32, 64, 4, 1, 3072><<<3072, 256, 0, stream>>>(
        x0T, E0, R0, V0, WTh0, WTl0, b0, x1);

    // L1: ES=2, CS=1, NT=4; edges/block=8; WGB=1536 -> 1536 blocks (6144 waves)
    hipMemsetAsync(x2, 0, (size_t)4194304 * 4, stream);
    conv_pool_mfma<32, 64, 288, 2, 1, 1536><<<1536, 256, 0, stream>>>(
        x1, E1, R1, V1, WTh1, WTl1, b1, x2);

    // L2 + L3 (x1 dead -> zero x3|x4 region in one memset)
    hipMemsetAsync(x3, 0, (size_t)3145728 * 4, stream);
    // L2: ES=2, CS=2, NT=4; edges/block=8; WGB=384 -> 768 blocks (3072 waves)
    conv_pool_mfma<64, 128, 576, 2, 2, 384><<<768, 256, 0, stream>>>(
        x2, E2, R2, V2, WTh2, WTl2, b2, x3);
    // L3: ES=4, CS=8, NT=2; edges/block=16; WGB=48 -> 384 blocks (1536 waves)
    conv_pool_mfma<128, 256, 1152, 4, 8, 48><<<384, 256, 0, stream>>>(
        x3, E3, R3, V3, WTh3, WTl3, b3, x4);

    // ---- final GEMM ----
    final_gemm_partial<<<256, 256, 0, stream>>>(x4, Wf, part);
    final_reduce<<<16, 256, 0, stream>>>(part, bf, out);
}